// Round 5
// baseline (394.715 us; speedup 1.0000x reference)
//
#include <hip/hip_runtime.h>

// 2-layer LSTM (B=2048,T=512,in=4,H=64) + FC + tanh. MFMA f16, wave-specialized.
// R14: anti-phase schedule, 2 barriers/round. R11-R13 post-mortem: round time
// = MFMA(496) + trans/VALU(630) + sync in EVERY in-phase scheme (barrier,
// setprio, spin-flags). m114: MFMA and VALU from different waves overlap only
// when concurrently issued -> create anti-phase by program order:
//   Phase1: L0-MFMA(r)      || L1-act -> h1(r-2)   (matrix || trans)
//   barrier A
//   Phase2: L0-act -> h0(r) || L1-MFMA step r-1    (trans || matrix)
//   barrier B
// L1 carries g-regs across barrier A; h1 single-buffered; h0 parity dbuf.
// Target round: max-of-pipes per phase + 2 barriers ~ 950-1100 cyc vs 1368.
//
// Safety: gate preacts bounded (|W|<=0.125,|h|<=1 -> |pre|<9 -> e in 2^±13,
// all CD products finite). Only exp2(c-path) needs the fmin guard.

#define HID 64
#define TSTEPS 512
#define MB 8
#define BLK 512
#define HSTR 88   // f16 words per h row; 176 B: 16B-aligned b128, stride 44 dw
#define LOG2E  1.4426950408889634f
#define LOG2E2 2.8853900817779268f

typedef _Float16 f16;
typedef _Float16 half8 __attribute__((ext_vector_type(8)));
typedef _Float16 half4 __attribute__((ext_vector_type(4)));
typedef float f32x4 __attribute__((ext_vector_type(4)));

__device__ __forceinline__ float tanh2(float y) {  // tanh(x), y = x*2*log2e
    return fmaf(2.0f, __builtin_amdgcn_rcpf(1.0f + __builtin_amdgcn_exp2f(-y)), -1.0f);
}

__global__ __launch_bounds__(BLK, 2) void lstm_mfma(
    const float* __restrict__ x,      // (2048, 512, 4)
    const float* __restrict__ w_ih0,  // (256, 4)
    const float* __restrict__ w_hh0,  // (256, 64)
    const float* __restrict__ b_ih0,  // (256,)
    const float* __restrict__ b_hh0,  // (256,)
    const float* __restrict__ w_ih1,  // (256, 64)
    const float* __restrict__ w_hh1,  // (256, 64)
    const float* __restrict__ b_ih1,  // (256,)
    const float* __restrict__ b_hh1,  // (256,)
    const float* __restrict__ fc_w,   // (64, 64)
    const float* __restrict__ fc_b,   // (64,)
    float* __restrict__ out)          // (2048, 64)
{
    __shared__ f16 xs[TSTEPS * MB * 4];     // 32 KB
    __shared__ f16 h0s[2][MB * HSTR];       // parity dbuf
    __shared__ f16 h1s[MB * HSTR];          // single buffer (L1-private timing)

    const int tid  = threadIdx.x;
    const int w    = tid >> 6;        // wave 0..7
    const int l    = tid & 63;
    const int quad = l >> 4;
    const int l15  = l & 15;
    const int wl   = w & 3;
    const bool isL0 = (w < 4);
    const int b0   = blockIdx.x * MB;

    // rotated duplicate-row map: rows 0-7 = batches 0-7,
    // rows 8-15 = batches {2,3,0,1,6,7,4,5} (act regs uniform {0,1}).
    const int RM = (l15 < 8) ? l15 : ((l15 & 4) | ((l15 + 2) & 3));

    // ---- stage x into LDS as f16 ----
    for (int it = tid; it < MB * TSTEPS; it += BLK) {
        const int m = it >> 9;
        const int t = it & 511;
        const float4 v = *((const float4*)x + (size_t)(b0 + m) * TSTEPS + t);
        *(half4*)(xs + (t * MB + m) * 4) =
            (half4){ (f16)v.x, (f16)v.y, (f16)v.z, (f16)v.w };
    }
    for (int it = tid; it < MB * HSTR; it += BLK) {
        h0s[0][it] = (f16)0.f; h0s[1][it] = (f16)0.f;
        h1s[it] = (f16)0.f;
    }

    // ---- B-fragments: 4 N-tiles x up-to-4 K-chunks, prescaled by log2e ----
    // B[k=quad*8+j][n=(wl+4*ti)*16+l15]; tile ti == gate ti of units wl*16+l15.
    // L0: [0]=x-proj(pad), [1-2]=w_hh0.  L1: [0-1]=w_ih1, [2-3]=w_hh1.
    half8 Bf[4][4];
    f32x4 biasv[4];                 // persistent C-operand
    const half8 Z = { (f16)0.f,(f16)0.f,(f16)0.f,(f16)0.f,
                      (f16)0.f,(f16)0.f,(f16)0.f,(f16)0.f };
    #pragma unroll
    for (int ti = 0; ti < 4; ++ti) {
        const int n = (wl + 4 * ti) * 16 + l15;
        const float sc = (ti == 2) ? LOG2E2 : LOG2E;   // g-gate feeds tanh path
        float bval;
        if (isL0) {
            bval = (b_ih0[n] + b_hh0[n]) * sc;
            half8 pz = Z;
            if (quad == 0) {
                const float4 v = *(const float4*)(w_ih0 + n * 4);
                pz[0] = (f16)(v.x * sc); pz[1] = (f16)(v.y * sc);
                pz[2] = (f16)(v.z * sc); pz[3] = (f16)(v.w * sc);
            }
            Bf[ti][0] = pz;
            #pragma unroll
            for (int ks = 0; ks < 2; ++ks) {
                const int ko = ks * 32 + quad * 8;
                const float4 a = *(const float4*)(w_hh0 + n * HID + ko);
                const float4 b = *(const float4*)(w_hh0 + n * HID + ko + 4);
                Bf[ti][1 + ks] = (half8){
                    (f16)(a.x*sc),(f16)(a.y*sc),(f16)(a.z*sc),(f16)(a.w*sc),
                    (f16)(b.x*sc),(f16)(b.y*sc),(f16)(b.z*sc),(f16)(b.w*sc) };
            }
            Bf[ti][3] = Z;
        } else {
            bval = (b_ih1[n] + b_hh1[n]) * sc;
            #pragma unroll
            for (int ks = 0; ks < 2; ++ks) {
                const int ko = ks * 32 + quad * 8;
                const float4 a = *(const float4*)(w_ih1 + n * HID + ko);
                const float4 b = *(const float4*)(w_ih1 + n * HID + ko + 4);
                Bf[ti][ks] = (half8){
                    (f16)(a.x*sc),(f16)(a.y*sc),(f16)(a.z*sc),(f16)(a.w*sc),
                    (f16)(b.x*sc),(f16)(b.y*sc),(f16)(b.z*sc),(f16)(b.w*sc) };
                const float4 c = *(const float4*)(w_hh1 + n * HID + ko);
                const float4 d = *(const float4*)(w_hh1 + n * HID + ko + 4);
                Bf[ti][2 + ks] = (half8){
                    (f16)(c.x*sc),(f16)(c.y*sc),(f16)(c.z*sc),(f16)(c.w*sc),
                    (f16)(d.x*sc),(f16)(d.y*sc),(f16)(d.z*sc),(f16)(d.w*sc) };
            }
        }
        biasv[ti] = (f32x4){ bval, bval, bval, bval };
    }

    // act ownership: lane (quad,l15) owns C/D regs {0,1} = batches
    // {mrow, mrow+1}, unit uu.  quad 0,1,2,3 -> mrow 0,4,2,6.
    const int  mrow = (quad & 1) * 4 + (quad & 2);
    const int  uu   = wl * 16 + l15;
    const int  hb   = RM * HSTR + quad * 8;   // A-frag base (rotated rows)
    float cst0 = 0.f, cst1 = 0.f;
    f32x4 g[4];

    auto load_x = [&](int r) -> half4 {
        return *(const half4*)(xs + (r * MB + RM) * 4);
    };
    auto l0_mfma = [&](half4 xv, const f16* h0rd) {
        __builtin_amdgcn_s_setprio(1);
        half8 ax = Z;
        if (quad == 0) { ax[0]=xv[0]; ax[1]=xv[1]; ax[2]=xv[2]; ax[3]=xv[3]; }
        const half8 A1 = *(const half8*)(h0rd + hb);
        const half8 A2 = *(const half8*)(h0rd + hb + 32);
        #pragma unroll
        for (int ti = 0; ti < 4; ++ti) {
            f32x4 acc;
            acc   = __builtin_amdgcn_mfma_f32_16x16x32_f16(ax, Bf[ti][0], biasv[ti], 0, 0, 0);
            acc   = __builtin_amdgcn_mfma_f32_16x16x32_f16(A1, Bf[ti][1], acc, 0, 0, 0);
            g[ti] = __builtin_amdgcn_mfma_f32_16x16x32_f16(A2, Bf[ti][2], acc, 0, 0, 0);
        }
        __builtin_amdgcn_s_setprio(0);
    };
    auto l1_mfma = [&](const f16* h0rd, const f16* h1rd) {
        __builtin_amdgcn_s_setprio(1);
        const half8 A1 = *(const half8*)(h0rd + hb);
        const half8 A2 = *(const half8*)(h0rd + hb + 32);
        const half8 A3 = *(const half8*)(h1rd + hb);
        const half8 A4 = *(const half8*)(h1rd + hb + 32);
        #pragma unroll
        for (int ti = 0; ti < 4; ++ti) {
            f32x4 acc;
            acc   = __builtin_amdgcn_mfma_f32_16x16x32_f16(A1, Bf[ti][0], biasv[ti], 0, 0, 0);
            acc   = __builtin_amdgcn_mfma_f32_16x16x32_f16(A2, Bf[ti][1], acc, 0, 0, 0);
            acc   = __builtin_amdgcn_mfma_f32_16x16x32_f16(A3, Bf[ti][2], acc, 0, 0, 0);
            g[ti] = __builtin_amdgcn_mfma_f32_16x16x32_f16(A4, Bf[ti][3], acc, 0, 0, 0);
        }
        __builtin_amdgcn_s_setprio(0);
    };
    // activations, 7 trans/cell (5 exp2 + 2 rcp):
    //   common denominator: c' = [c*(1+ei)(1+eg) + (1-eg)(1+ef)]
    //                           * rcp((1+ef)(1+ei)(1+eg))
    //   h = (1-ec)*rcp((1+eo)(1+ec)),  exp2 arg of ec clamped <= 126
    auto act_store = [&](f16* dst) {
        #pragma unroll
        for (int j = 0; j < 2; ++j) {
            const float ei = __builtin_amdgcn_exp2f(-g[0][j]);
            const float ef = __builtin_amdgcn_exp2f(-g[1][j]);
            const float eg = __builtin_amdgcn_exp2f(-g[2][j]);
            const float eo = __builtin_amdgcn_exp2f(-g[3][j]);
            float& c = j ? cst1 : cst0;
            const float af = 1.0f + ef;
            const float P  = (1.0f + ei) * (1.0f + eg);
            const float N  = fmaf(c * P, 1.0f, (1.0f - eg) * af);  // c*P + (1-eg)*af
            c = N * __builtin_amdgcn_rcpf(P * af);
            const float ym = fminf(-LOG2E2 * c, 126.0f);
            const float ec = __builtin_amdgcn_exp2f(ym);
            const float r2 = __builtin_amdgcn_rcpf((1.0f + eo) * (1.0f + ec));
            dst[(mrow + j) * HSTR + uu] = (f16)((1.0f - ec) * r2);
        }
    };

    __syncthreads();   // staging complete

    half4 xv;
    if (isL0) xv = load_x(0);

    // ---- main rounds: anti-phase, 2 barriers/round ----
    // Phase1: L0-MFMA(r) [h0(r-1)] || L1-act -> h1(r-2)   (r>=2)
    // Phase2: L0-act -> h0(r)      || L1-MFMA step r-1 [h0(r-1), h1(r-2)] (r>=1)
    #pragma unroll 1
    for (int r = 0; r < TSTEPS; ++r) {
        if (isL0) {
            l0_mfma(xv, h0s[(r + 1) & 1]);     // h0(r-1) at slot (r-1)&1
            xv = load_x((r + 1) & 511);
        } else if (r >= 2) {
            act_store(h1s);                    // h1(r-2)
        }
        __syncthreads();                       // barrier A
        if (isL0) {
            act_store(h0s[r & 1]);             // h0(r)
        } else if (r >= 1) {
            l1_mfma(h0s[(r + 1) & 1], h1s);    // step r-1
        }
        __syncthreads();                       // barrier B
    }

    // ---- L1 drain: act->h1(510); MFMA step 511; act->h1(511) ----
    if (!isL0) act_store(h1s);                 // h1(510)
    __syncthreads();
    if (!isL0) {
        l1_mfma(h0s[1], h1s);                  // step 511: h0(511) at slot 1
        act_store(h1s);                        // h1(511)
    }
    __syncthreads();

    // ---- epilogue: out[b][v] = tanh(h1(511) . fc_w[v] + fc_b[v]) ----
    {
        const int v = tid & 63;
        const int m = tid >> 6;
        float a = fc_b[v];
        const f16* hp = h1s + m * HSTR;
        const float4* wp = (const float4*)(fc_w + v * HID);
        #pragma unroll
        for (int kk = 0; kk < HID / 4; ++kk) {
            const float4 wv = wp[kk];
            a += (float)hp[kk * 4 + 0] * wv.x + (float)hp[kk * 4 + 1] * wv.y
               + (float)hp[kk * 4 + 2] * wv.z + (float)hp[kk * 4 + 3] * wv.w;
        }
        out[(size_t)(b0 + m) * HID + v] = tanh2(a * LOG2E2);
    }
}

extern "C" void kernel_launch(void* const* d_in, const int* in_sizes, int n_in,
                              void* d_out, int out_size, void* d_ws, size_t ws_size,
                              hipStream_t stream) {
    const float* x     = (const float*)d_in[0];
    const float* w_ih0 = (const float*)d_in[1];
    const float* w_hh0 = (const float*)d_in[2];
    const float* b_ih0 = (const float*)d_in[3];
    const float* b_hh0 = (const float*)d_in[4];
    const float* w_ih1 = (const float*)d_in[5];
    const float* w_hh1 = (const float*)d_in[6];
    const float* b_ih1 = (const float*)d_in[7];
    const float* b_hh1 = (const float*)d_in[8];
    const float* fc_w  = (const float*)d_in[9];
    const float* fc_b  = (const float*)d_in[10];
    float* out = (float*)d_out;

    const int B = in_sizes[0] / (TSTEPS * 4);   // 2048
    lstm_mfma<<<dim3(B / MB), dim3(BLK), 0, stream>>>(
        x, w_ih0, w_hh0, b_ih0, b_hh0, w_ih1, w_hh1, b_ih1, b_hh1, fc_w, fc_b, out);
}

// Round 6
// 368.141 us; speedup vs baseline: 1.0722x; 1.0722x over previous
//
#include <hip/hip_runtime.h>

// 2-layer LSTM (B=2048,T=512,in=4,H=64) + FC + tanh. MFMA f16.
// R15: LAYER-FUSED waves, intra-wave MFMA||trans overlap. R11-R14 proved
// inter-wave MFMA+trans co-issue never happens (round = sum of pipe times in
// every scheme; barrier ~250-300cyc at 8 waves). Fix: give each wave BOTH an
// MFMA stream and an independent trans stream. 4 waves (BLK=256), wave wl owns
// units [16wl,16wl+16) of BOTH layers:
//   Phase A(r): L1-act(r-2) [g1 regs]  ||  L0-MFMA(r)      -> bar
//   Phase B(r): L0-act(r) -> h0(r)     ||  L1-MFMA(r-1)    -> bar
// In-order wave + scoreboard: trans fills MFMA issue gaps + ds_read latency.
// h0: depth-4 ring (slot r&3); h1: parity (slot r&1); g1 carried in regs
// across B(r)->A(r+1). Per-SIMD work unchanged (28 MFMA + 28 cells/round);
// round model max(264,212)+max(240,283)+2 bar(4-wave) ~ 840 cyc vs 1368.
//
// Safety: gate preacts bounded (|W|<=0.125,|h|<=1 -> |pre|<9 -> e in 2^±13,
// all CD products finite). Only exp2(c-path) needs the fmin guard.

#define HID 64
#define TSTEPS 512
#define MB 8
#define BLK 256
#define HSTR 88   // f16 words per h row; 176 B: 16B-aligned b128, stride 44 dw
#define LOG2E  1.4426950408889634f
#define LOG2E2 2.8853900817779268f

typedef _Float16 f16;
typedef _Float16 half8 __attribute__((ext_vector_type(8)));
typedef _Float16 half4 __attribute__((ext_vector_type(4)));
typedef float f32x4 __attribute__((ext_vector_type(4)));

__device__ __forceinline__ float tanh2(float y) {  // tanh(x), y = x*2*log2e
    return fmaf(2.0f, __builtin_amdgcn_rcpf(1.0f + __builtin_amdgcn_exp2f(-y)), -1.0f);
}

__global__ __launch_bounds__(BLK, 1) void lstm_mfma(
    const float* __restrict__ x,      // (2048, 512, 4)
    const float* __restrict__ w_ih0,  // (256, 4)
    const float* __restrict__ w_hh0,  // (256, 64)
    const float* __restrict__ b_ih0,  // (256,)
    const float* __restrict__ b_hh0,  // (256,)
    const float* __restrict__ w_ih1,  // (256, 64)
    const float* __restrict__ w_hh1,  // (256, 64)
    const float* __restrict__ b_ih1,  // (256,)
    const float* __restrict__ b_hh1,  // (256,)
    const float* __restrict__ fc_w,   // (64, 64)
    const float* __restrict__ fc_b,   // (64,)
    float* __restrict__ out)          // (2048, 64)
{
    __shared__ f16 xs[TSTEPS * MB * 4];     // 32 KB
    __shared__ f16 h0s[4][MB * HSTR];       // depth-4 ring
    __shared__ f16 h1s[2][MB * HSTR];       // parity

    const int tid  = threadIdx.x;
    const int wl   = tid >> 6;        // wave 0..3, owns units [16wl,16wl+16)
    const int l    = tid & 63;
    const int quad = l >> 4;
    const int l15  = l & 15;
    const int b0   = blockIdx.x * MB;

    // rotated duplicate-row map: rows 0-7 = batches 0-7,
    // rows 8-15 = batches {2,3,0,1,6,7,4,5} (act regs uniform {0,1}).
    const int RM = (l15 < 8) ? l15 : ((l15 & 4) | ((l15 + 2) & 3));

    // ---- stage x into LDS as f16 ----
    for (int it = tid; it < MB * TSTEPS; it += BLK) {
        const int m = it >> 9;
        const int t = it & 511;
        const float4 v = *((const float4*)x + (size_t)(b0 + m) * TSTEPS + t);
        *(half4*)(xs + (t * MB + m) * 4) =
            (half4){ (f16)v.x, (f16)v.y, (f16)v.z, (f16)v.w };
    }
    for (int it = tid; it < MB * HSTR; it += BLK) {
        h0s[0][it] = (f16)0.f; h0s[1][it] = (f16)0.f;
        h0s[2][it] = (f16)0.f; h0s[3][it] = (f16)0.f;
        h1s[0][it] = (f16)0.f; h1s[1][it] = (f16)0.f;
    }

    // ---- B-fragments, BOTH layers, prescaled by log2e ----
    // B[k=quad*8+j][n=(wl+4*ti)*16+l15]; tile ti == gate ti of units wl*16+l15.
    // L0: B0[ti][0]=x-proj(pad K4), [1-2]=w_hh0.  L1: B1[ti][0-1]=w_ih1,
    // [2-3]=w_hh1.
    half8 B0[4][3];
    half8 B1[4][4];
    f32x4 bias0[4], bias1[4];
    const half8 Z = { (f16)0.f,(f16)0.f,(f16)0.f,(f16)0.f,
                      (f16)0.f,(f16)0.f,(f16)0.f,(f16)0.f };
    #pragma unroll
    for (int ti = 0; ti < 4; ++ti) {
        const int n = (wl + 4 * ti) * 16 + l15;
        const float sc = (ti == 2) ? LOG2E2 : LOG2E;   // g-gate feeds tanh path
        {   // layer 0
            const float bval = (b_ih0[n] + b_hh0[n]) * sc;
            half8 pz = Z;
            if (quad == 0) {
                const float4 v = *(const float4*)(w_ih0 + n * 4);
                pz[0] = (f16)(v.x * sc); pz[1] = (f16)(v.y * sc);
                pz[2] = (f16)(v.z * sc); pz[3] = (f16)(v.w * sc);
            }
            B0[ti][0] = pz;
            #pragma unroll
            for (int ks = 0; ks < 2; ++ks) {
                const int ko = ks * 32 + quad * 8;
                const float4 a = *(const float4*)(w_hh0 + n * HID + ko);
                const float4 b = *(const float4*)(w_hh0 + n * HID + ko + 4);
                B0[ti][1 + ks] = (half8){
                    (f16)(a.x*sc),(f16)(a.y*sc),(f16)(a.z*sc),(f16)(a.w*sc),
                    (f16)(b.x*sc),(f16)(b.y*sc),(f16)(b.z*sc),(f16)(b.w*sc) };
            }
            bias0[ti] = (f32x4){ bval, bval, bval, bval };
        }
        {   // layer 1
            const float bval = (b_ih1[n] + b_hh1[n]) * sc;
            #pragma unroll
            for (int ks = 0; ks < 2; ++ks) {
                const int ko = ks * 32 + quad * 8;
                const float4 a = *(const float4*)(w_ih1 + n * HID + ko);
                const float4 b = *(const float4*)(w_ih1 + n * HID + ko + 4);
                B1[ti][ks] = (half8){
                    (f16)(a.x*sc),(f16)(a.y*sc),(f16)(a.z*sc),(f16)(a.w*sc),
                    (f16)(b.x*sc),(f16)(b.y*sc),(f16)(b.z*sc),(f16)(b.w*sc) };
                const float4 c = *(const float4*)(w_hh1 + n * HID + ko);
                const float4 d = *(const float4*)(w_hh1 + n * HID + ko + 4);
                B1[ti][2 + ks] = (half8){
                    (f16)(c.x*sc),(f16)(c.y*sc),(f16)(c.z*sc),(f16)(c.w*sc),
                    (f16)(d.x*sc),(f16)(d.y*sc),(f16)(d.z*sc),(f16)(d.w*sc) };
            }
            bias1[ti] = (f32x4){ bval, bval, bval, bval };
        }
    }

    // act ownership: lane (quad,l15) owns C/D regs {0,1} = batches
    // {mrow, mrow+1}, unit uu.  quad 0,1,2,3 -> mrow 0,4,2,6.
    const int  mrow = (quad & 1) * 4 + (quad & 2);
    const int  uu   = wl * 16 + l15;
    const int  hb   = RM * HSTR + quad * 8;   // A-frag base (rotated rows)
    float c00 = 0.f, c01 = 0.f;               // L0 cell states
    float c10 = 0.f, c11 = 0.f;               // L1 cell states
    f32x4 g0[4], g1[4];

    auto load_x = [&](int r) -> half4 {
        return *(const half4*)(xs + (r * MB + RM) * 4);
    };
    auto l0_mfma = [&](half4 xv, half8 A1, half8 A2) {
        half8 ax = Z;
        if (quad == 0) { ax[0]=xv[0]; ax[1]=xv[1]; ax[2]=xv[2]; ax[3]=xv[3]; }
        #pragma unroll
        for (int ti = 0; ti < 4; ++ti) {
            f32x4 acc;
            acc    = __builtin_amdgcn_mfma_f32_16x16x32_f16(ax, B0[ti][0], bias0[ti], 0, 0, 0);
            acc    = __builtin_amdgcn_mfma_f32_16x16x32_f16(A1, B0[ti][1], acc, 0, 0, 0);
            g0[ti] = __builtin_amdgcn_mfma_f32_16x16x32_f16(A2, B0[ti][2], acc, 0, 0, 0);
        }
    };
    auto l1_mfma = [&](half8 A1, half8 A2, half8 A3, half8 A4) {
        #pragma unroll
        for (int ti = 0; ti < 4; ++ti) {
            f32x4 acc;
            acc    = __builtin_amdgcn_mfma_f32_16x16x32_f16(A1, B1[ti][0], bias1[ti], 0, 0, 0);
            acc    = __builtin_amdgcn_mfma_f32_16x16x32_f16(A2, B1[ti][1], acc, 0, 0, 0);
            acc    = __builtin_amdgcn_mfma_f32_16x16x32_f16(A3, B1[ti][2], acc, 0, 0, 0);
            g1[ti] = __builtin_amdgcn_mfma_f32_16x16x32_f16(A4, B1[ti][3], acc, 0, 0, 0);
        }
    };
    // activations, 7 trans/cell (5 exp2 + 2 rcp):
    //   common denominator: c' = [c*(1+ei)(1+eg) + (1-eg)(1+ef)]
    //                           * rcp((1+ef)(1+ei)(1+eg))
    //   h = (1-ec)*rcp((1+eo)(1+ec)),  exp2 arg of ec clamped <= 126
    auto act_store = [&](const f32x4* gg, f16* dst, float& ca, float& cb) {
        #pragma unroll
        for (int j = 0; j < 2; ++j) {
            const float ei = __builtin_amdgcn_exp2f(-gg[0][j]);
            const float ef = __builtin_amdgcn_exp2f(-gg[1][j]);
            const float eg = __builtin_amdgcn_exp2f(-gg[2][j]);
            const float eo = __builtin_amdgcn_exp2f(-gg[3][j]);
            float& c = j ? cb : ca;
            const float af = 1.0f + ef;
            const float P  = (1.0f + ei) * (1.0f + eg);
            const float N  = fmaf(c * P, 1.0f, (1.0f - eg) * af);  // c*P + (1-eg)*af
            c = N * __builtin_amdgcn_rcpf(P * af);
            const float ym = fminf(-LOG2E2 * c, 126.0f);
            const float ec = __builtin_amdgcn_exp2f(ym);
            const float r2 = __builtin_amdgcn_rcpf((1.0f + eo) * (1.0f + ec));
            dst[(mrow + j) * HSTR + uu] = (f16)((1.0f - ec) * r2);
        }
    };

    __syncthreads();   // staging complete

    half4 xv = load_x(0);

    // ---- main rounds r = 0..511 ----
    // A(r): L1-act(r-2) -> h1s[r&1]  ||  L0-MFMA(r) reads h0s[(r+3)&3]
    // B(r): L0-act(r)   -> h0s[r&3]  ||  L1-MFMA(r-1) reads h0s[(r+3)&3], h1s[r&1]
    #pragma unroll 1
    for (int r = 0; r < TSTEPS; ++r) {
        // ---- Phase A ----
        const f16* h0rd = h0s[(r + 3) & 3];
        const half8 A1 = *(const half8*)(h0rd + hb);        // h0(r-1) frags
        const half8 A2 = *(const half8*)(h0rd + hb + 32);
        if (r >= 2) act_store(g1, h1s[r & 1], c10, c11);    // h1(r-2), trans
        l0_mfma(xv, A1, A2);                                // matrix, fills g0
        __syncthreads();
        // ---- Phase B ----
        const f16* h1rd = h1s[r & 1];
        const half8 A3 = *(const half8*)(h1rd + hb);        // h1(r-2) frags
        const half8 A4 = *(const half8*)(h1rd + hb + 32);
        act_store(g0, h0s[r & 3], c00, c01);                // h0(r), trans
        l1_mfma(A1, A2, A3, A4);                            // matrix, step r-1
                                                            // (r=0: zeros, g1
                                                            //  discarded)
        xv = load_x((r + 1) & 511);
        __syncthreads();
    }

    // ---- drain: h1(510); MFMA step 511; h1(511) ----
    act_store(g1, h1s[0], c10, c11);                        // h1(510), slot 0
    __syncthreads();
    {
        const f16* h0rd = h0s[3];                           // h0(511), slot 3
        const half8 A1 = *(const half8*)(h0rd + hb);
        const half8 A2 = *(const half8*)(h0rd + hb + 32);
        const half8 A3 = *(const half8*)(h1s[0] + hb);      // h1(510)
        const half8 A4 = *(const half8*)(h1s[0] + hb + 32);
        l1_mfma(A1, A2, A3, A4);                            // step 511
        act_store(g1, h1s[1], c10, c11);                    // h1(511), slot 1
    }
    __syncthreads();

    // ---- epilogue: out[b][v] = tanh(h1(511) . fc_w[v] + fc_b[v]) ----
    for (int it = tid; it < MB * HID; it += BLK) {
        const int v = it & 63;
        const int m = it >> 6;
        float a = fc_b[v];
        const f16* hp = h1s[1] + m * HSTR;
        const float4* wp = (const float4*)(fc_w + v * HID);
        #pragma unroll
        for (int kk = 0; kk < HID / 4; ++kk) {
            const float4 wv = wp[kk];
            a += (float)hp[kk * 4 + 0] * wv.x + (float)hp[kk * 4 + 1] * wv.y
               + (float)hp[kk * 4 + 2] * wv.z + (float)hp[kk * 4 + 3] * wv.w;
        }
        out[(size_t)(b0 + m) * HID + v] = tanh2(a * LOG2E2);
    }
}

extern "C" void kernel_launch(void* const* d_in, const int* in_sizes, int n_in,
                              void* d_out, int out_size, void* d_ws, size_t ws_size,
                              hipStream_t stream) {
    const float* x     = (const float*)d_in[0];
    const float* w_ih0 = (const float*)d_in[1];
    const float* w_hh0 = (const float*)d_in[2];
    const float* b_ih0 = (const float*)d_in[3];
    const float* b_hh0 = (const float*)d_in[4];
    const float* w_ih1 = (const float*)d_in[5];
    const float* w_hh1 = (const float*)d_in[6];
    const float* b_ih1 = (const float*)d_in[7];
    const float* b_hh1 = (const float*)d_in[8];
    const float* fc_w  = (const float*)d_in[9];
    const float* fc_b  = (const float*)d_in[10];
    float* out = (float*)d_out;

    const int B = in_sizes[0] / (TSTEPS * 4);   // 2048
    lstm_mfma<<<dim3(B / MB), dim3(BLK), 0, stream>>>(
        x, w_ih0, w_hh0, b_ih0, b_hh0, w_ih1, w_hh1, b_ih1, b_hh1, fc_w, fc_b, out);
}